// Round 2
// baseline (1306.521 us; speedup 1.0000x reference)
//
#include <hip/hip_runtime.h>
#include <math.h>

#define SBS 256
#define SIT 8
#define SCHUNK (SBS*SIT)   // 2048 elements per scan block

// ---------------- gcn_norm preprocessing ----------------

__global__ void k_count(const int* __restrict__ col, float* __restrict__ deg, int E){
  int e = blockIdx.x*256 + threadIdx.x;
  if(e < E) atomicAdd(&deg[col[e]], 1.0f);
}

__global__ void k_dis(const float* __restrict__ deg, float* __restrict__ dis, int N){
  int i = blockIdx.x*256 + threadIdx.x;
  if(i < N){ float d = deg[i]; dis[i] = d > 0.f ? 1.0f/sqrtf(d) : 0.f; }
}

__global__ void k_scan_a(const float* __restrict__ deg, int* __restrict__ bsums, int N){
  __shared__ int ls[SBS/64];
  int base = blockIdx.x*SCHUNK + threadIdx.x*SIT;
  int s = 0;
  #pragma unroll
  for(int j=0;j<SIT;j++){ int i=base+j; if(i<N) s += (int)deg[i]; }
  #pragma unroll
  for(int o=32;o>0;o>>=1) s += __shfl_down(s,o);
  int lane = threadIdx.x & 63, w = threadIdx.x >> 6;
  if(lane==0) ls[w]=s;
  __syncthreads();
  if(threadIdx.x==0){ int t=0; for(int k2=0;k2<SBS/64;k2++) t+=ls[k2]; bsums[blockIdx.x]=t; }
}

__global__ void k_scan_b(const int* __restrict__ bsums, int* __restrict__ boffs,
                         int* __restrict__ rowptr, int NB, int N){
  int lane = threadIdx.x; // 64 threads
  int v = (lane < NB) ? bsums[lane] : 0;
  int incl = v;
  #pragma unroll
  for(int o=1;o<64;o<<=1){ int t = __shfl_up(incl,o); if(lane>=o) incl += t; }
  if(lane < NB) boffs[lane] = incl - v;
  if(lane == 63) rowptr[N] = incl;   // total == E
}

__global__ void k_scan_c(const float* __restrict__ deg, const int* __restrict__ boffs,
                         int* __restrict__ rowptr, int* __restrict__ cur, int N){
  __shared__ int ts[SBS];
  int tid = threadIdx.x;
  int base = blockIdx.x*SCHUNK + tid*SIT;
  int v[SIT]; int s=0;
  #pragma unroll
  for(int j=0;j<SIT;j++){ int i=base+j; int d=(i<N)?(int)deg[i]:0; v[j]=s; s+=d; }
  ts[tid]=s; __syncthreads();
  for(int o=1;o<SBS;o<<=1){
    int t=(tid>=o)?ts[tid-o]:0; __syncthreads();
    ts[tid]+=t; __syncthreads();
  }
  int texcl = ts[tid]-s;
  int off = boffs[blockIdx.x]+texcl;
  #pragma unroll
  for(int j=0;j<SIT;j++){ int i=base+j; if(i<N){int r=off+v[j]; rowptr[i]=r; cur[i]=r;} }
}

__global__ void k_fill(const int* __restrict__ row, const int* __restrict__ col,
                       const float* __restrict__ dis, int* __restrict__ cur,
                       int* __restrict__ csrc, float* __restrict__ cw, int E){
  int e = blockIdx.x*256+threadIdx.x;
  if(e<E){
    int r=row[e], c=col[e];
    int p = atomicAdd(&cur[c],1);
    csrc[p]=r;
    cw[p]=dis[r]*dis[c];
  }
}

// ---------------- SpMM gather: dst[n] = sum_e w[e]*src[csrc[e]] ----------------

__global__ void __launch_bounds__(256) k_spmm(const float* __restrict__ src, float* __restrict__ dst,
                       const int* __restrict__ rowptr, const int* __restrict__ csrc,
                       const float* __restrict__ cw, int N){
  int wid = threadIdx.x>>6, lane = threadIdx.x&63;
  int n = blockIdx.x*4 + wid;
  if(n>=N) return;
  int s = rowptr[n], e = rowptr[n+1];
  float ax=0.f, ay=0.f;
  for(int b=s; b<e; b+=64){
    int m = e-b; if(m>64) m=64;
    int idx=0; float wt=0.f;
    if(lane<m){ idx=csrc[b+lane]; wt=cw[b+lane]; }
    for(int j=0;j<m;j++){
      int r = __shfl(idx,j);
      float wg = __shfl(wt,j);
      const float2 hv = *reinterpret_cast<const float2*>(src + (size_t)r*128 + lane*2);
      ax += wg*hv.x; ay += wg*hv.y;
    }
  }
  float2 o; o.x=ax; o.y=ay;
  *reinterpret_cast<float2*>(dst + (size_t)n*128 + lane*2) = o;
}

// ---------------- layer 1 fused GEMM: out1 = relu([x|h1|h2|h3] @ Wstack + b1) ----------------

__global__ void __launch_bounds__(256) k_gemm_l1(
    const float* __restrict__ s0, const float* __restrict__ s1,
    const float* __restrict__ s2, const float* __restrict__ s3,
    const float* __restrict__ w,   // [4][128][128] row-major [k][in][out]
    const float* __restrict__ bias, float* __restrict__ out, int N){
  __shared__ __align__(16) float hs[32][128];
  __shared__ __align__(16) float wc[32][128];
  int tid = threadIdx.x;
  int cg = (tid & 31) * 4;   // output col base (0..124)
  int ng = (tid >> 5);       // node group 0..7 -> nodes ng*4..ng*4+3
  int nbase = blockIdx.x * 32;
  float acc[4][4];
  #pragma unroll
  for(int i=0;i<4;i++){
    #pragma unroll
    for(int j=0;j<4;j++) acc[i][j]=0.f;
  }
  const float* srcs[4] = {s0,s1,s2,s3};
  #pragma unroll 1
  for(int si=0; si<4; si++){
    const float* src = srcs[si];
    __syncthreads();
    #pragma unroll
    for(int j=0;j<4;j++){
      int t = tid + j*256;               // 0..1023 float4 slots
      int r = t >> 5, c4 = (t & 31) * 4;
      int n = nbase + r;
      float4 v = make_float4(0.f,0.f,0.f,0.f);
      if(n < N) v = *(const float4*)&src[(size_t)n*128 + c4];
      *(float4*)&hs[r][c4] = v;
    }
    const float* wsrc = w + (size_t)si*128*128;
    #pragma unroll 1
    for(int kc=0; kc<4; kc++){
      __syncthreads();
      #pragma unroll
      for(int j=0;j<4;j++){
        int t = tid + j*256;
        int r = t >> 5, c4 = (t & 31) * 4;
        *(float4*)&wc[r][c4] = *(const float4*)&wsrc[(size_t)(kc*32+r)*128 + c4];
      }
      __syncthreads();
      #pragma unroll
      for(int k=0;k<32;k++){
        float4 wv = *(float4*)&wc[k][cg];
        #pragma unroll
        for(int i=0;i<4;i++){
          float hv = hs[ng*4+i][kc*32+k];   // FIXED: was hs[ng*4+i][k]
          acc[i][0] += hv*wv.x; acc[i][1] += hv*wv.y;
          acc[i][2] += hv*wv.z; acc[i][3] += hv*wv.w;
        }
      }
    }
  }
  float4 bv = *(const float4*)&bias[cg];
  #pragma unroll
  for(int i=0;i<4;i++){
    int n = nbase + ng*4 + i;
    if(n < N){
      float4 o;
      o.x = fmaxf(acc[i][0]+bv.x, 0.f);
      o.y = fmaxf(acc[i][1]+bv.y, 0.f);
      o.z = fmaxf(acc[i][2]+bv.z, 0.f);
      o.w = fmaxf(acc[i][3]+bv.w, 0.f);
      *(float4*)&out[(size_t)n*128 + cg] = o;
    }
  }
}

// ------------ layer 2 fused GEMM + log_softmax: out = lsm([h|g1|g2|g3] @ Wstack + b2) ------------

__global__ void __launch_bounds__(320) k_gemm_l2(
    const float* __restrict__ s0, const float* __restrict__ s1,
    const float* __restrict__ s2, const float* __restrict__ s3,
    const float* __restrict__ w,   // [4][128][40]
    const float* __restrict__ bias, float* __restrict__ out, int N){
  __shared__ __align__(16) float hs[64*132];   // 64 nodes x 128, pitch 132 (bank spread)
  __shared__ __align__(16) float wb[128*40];   // W chunk; later reused as score tile [64][41]
  __shared__ float sm[64], sl[64];
  int tid = threadIdx.x;
  int g = tid % 10;          // col group: cols 4g..4g+3
  int q = tid / 10;          // node pair 0..31
  int nbase = blockIdx.x * 64;
  float acc[2][4];
  #pragma unroll
  for(int i=0;i<2;i++){
    #pragma unroll
    for(int j=0;j<4;j++) acc[i][j]=0.f;
  }
  const float* srcs[4] = {s0,s1,s2,s3};
  #pragma unroll 1
  for(int si=0; si<4; si++){
    const float* src = srcs[si];
    __syncthreads();
    for(int t=tid; t<2048; t+=320){          // 64x128 = 2048 float4
      int r = t >> 5, c4 = (t & 31)*4;
      int n = nbase + r;
      float4 v = make_float4(0.f,0.f,0.f,0.f);
      if(n < N) v = *(const float4*)&src[(size_t)n*128 + c4];
      *(float4*)&hs[r*132 + c4] = v;
    }
    const float* wsrc = w + (size_t)si*128*40;
    for(int t=tid; t<1280; t+=320){          // 128x40 = 1280 float4
      *(float4*)&wb[t*4] = *(const float4*)&wsrc[(size_t)t*4];
    }
    __syncthreads();
    #pragma unroll 4
    for(int k=0;k<128;k++){
      float4 wv = *(float4*)&wb[k*40 + g*4];
      float h0 = hs[(q*2  )*132 + k];
      float h1 = hs[(q*2+1)*132 + k];
      acc[0][0]+=h0*wv.x; acc[0][1]+=h0*wv.y; acc[0][2]+=h0*wv.z; acc[0][3]+=h0*wv.w;
      acc[1][0]+=h1*wv.x; acc[1][1]+=h1*wv.y; acc[1][2]+=h1*wv.z; acc[1][3]+=h1*wv.w;
    }
  }
  float4 bv = *(const float4*)&bias[g*4];
  #pragma unroll
  for(int i=0;i<2;i++){
    acc[i][0]+=bv.x; acc[i][1]+=bv.y; acc[i][2]+=bv.z; acc[i][3]+=bv.w;
  }
  __syncthreads();                 // done with wb as weights
  // stash scores into wb reused as [64][41]
  #pragma unroll
  for(int i=0;i<2;i++){
    int nl = q*2+i;
    wb[nl*41 + g*4 + 0] = acc[i][0];
    wb[nl*41 + g*4 + 1] = acc[i][1];
    wb[nl*41 + g*4 + 2] = acc[i][2];
    wb[nl*41 + g*4 + 3] = acc[i][3];
  }
  __syncthreads();
  if(tid < 64){
    int n = nbase + tid;
    if(n < N){
      float m = -1e30f;
      for(int j=0;j<40;j++) m = fmaxf(m, wb[tid*41+j]);
      float ss = 0.f;
      for(int j=0;j<40;j++) ss += expf(wb[tid*41+j]-m);
      sm[tid] = m; sl[tid] = logf(ss);
    }
  }
  __syncthreads();
  #pragma unroll
  for(int i=0;i<2;i++){
    int nl = q*2+i; int n = nbase + nl;
    if(n < N){
      float m = sm[nl], l = sl[nl];
      float4 o;
      o.x = acc[i][0]-m-l; o.y = acc[i][1]-m-l;
      o.z = acc[i][2]-m-l; o.w = acc[i][3]-m-l;
      *(float4*)&out[(size_t)n*40 + g*4] = o;
    }
  }
}

// ---------------- host ----------------

extern "C" void kernel_launch(void* const* d_in, const int* in_sizes, int n_in,
                              void* d_out, int out_size, void* d_ws, size_t ws_size,
                              hipStream_t stream){
  const float* x  = (const float*)d_in[0];
  const int*   ei = (const int*)d_in[1];
  const float* w1 = (const float*)d_in[2];
  const float* b1 = (const float*)d_in[3];
  const float* w2 = (const float*)d_in[4];
  const float* b2 = (const float*)d_in[5];
  float* out = (float*)d_out;
  int N = in_sizes[0] / 128;
  int E = in_sizes[1] / 2;
  const int* rowv = ei;
  const int* colv = ei + E;

  char* wsp = (char*)d_ws;
  size_t off = 0;
  auto alloc = [&](size_t bytes)->void*{
    void* p = wsp + off;
    off = (off + bytes + 255) & ~(size_t)255;
    return p;
  };
  float* deg    = (float*)alloc((size_t)N*4);
  float* dis    = (float*)alloc((size_t)N*4);
  int*   rowptr = (int*)  alloc((size_t)(N+1)*4);
  int*   cur    = (int*)  alloc((size_t)N*4);
  int*   bsums  = (int*)  alloc(512);
  int*   boffs  = (int*)  alloc(512);
  int*   csrc   = (int*)  alloc((size_t)E*4);
  float* cw     = (float*)alloc((size_t)E*4);
  float* h1     = (float*)alloc((size_t)N*128*4);
  float* h2     = (float*)alloc((size_t)N*128*4);
  float* h3     = (float*)alloc((size_t)N*128*4);
  float* out1   = (float*)alloc((size_t)N*128*4);
  (void)ws_size;

  int eb = (E+255)/256;
  int nb = (N+SCHUNK-1)/SCHUNK;

  hipMemsetAsync(deg, 0, (size_t)N*4, stream);
  k_count <<<eb, 256, 0, stream>>>(colv, deg, E);
  k_dis   <<<(N+255)/256, 256, 0, stream>>>(deg, dis, N);
  k_scan_a<<<nb, SBS, 0, stream>>>(deg, bsums, N);
  k_scan_b<<<1, 64, 0, stream>>>(bsums, boffs, rowptr, nb, N);
  k_scan_c<<<nb, SBS, 0, stream>>>(deg, boffs, rowptr, cur, N);
  k_fill  <<<eb, 256, 0, stream>>>(rowv, colv, dis, cur, csrc, cw, E);

  int sg = (N+3)/4;
  // layer 1 propagations
  k_spmm<<<sg, 256, 0, stream>>>(x,  h1, rowptr, csrc, cw, N);
  k_spmm<<<sg, 256, 0, stream>>>(h1, h2, rowptr, csrc, cw, N);
  k_spmm<<<sg, 256, 0, stream>>>(h2, h3, rowptr, csrc, cw, N);
  k_gemm_l1<<<(N+31)/32, 256, 0, stream>>>(x, h1, h2, h3, w1, b1, out1, N);
  // layer 2 propagations
  k_spmm<<<sg, 256, 0, stream>>>(out1, h1, rowptr, csrc, cw, N);
  k_spmm<<<sg, 256, 0, stream>>>(h1,   h2, rowptr, csrc, cw, N);
  k_spmm<<<sg, 256, 0, stream>>>(h2,   h3, rowptr, csrc, cw, N);
  k_gemm_l2<<<(N+63)/64, 320, 0, stream>>>(out1, h1, h2, h3, w2, b2, out, N);
}

// Round 3
// 806.043 us; speedup vs baseline: 1.6209x; 1.6209x over previous
//
#include <hip/hip_runtime.h>
#include <math.h>

#define SBS 256
#define SIT 8
#define SCHUNK (SBS*SIT)

typedef __bf16 bf16x8 __attribute__((ext_vector_type(8)));
typedef float  f32x4  __attribute__((ext_vector_type(4)));

__device__ __forceinline__ unsigned short f2bf(float f){
  unsigned u = __float_as_uint(f);
  unsigned r = (u + 0x7fffu + ((u>>16)&1u)) >> 16;
  return (unsigned short)r;
}
__device__ __forceinline__ float bflo(unsigned v){ return __uint_as_float(v<<16); }
__device__ __forceinline__ float bfhi(unsigned v){ return __uint_as_float(v & 0xffff0000u); }

// ---------------- gcn_norm preprocessing (unchanged) ----------------

__global__ void k_count(const int* __restrict__ col, float* __restrict__ deg, int E){
  int e = blockIdx.x*256 + threadIdx.x;
  if(e < E) atomicAdd(&deg[col[e]], 1.0f);
}

__global__ void k_dis(const float* __restrict__ deg, float* __restrict__ dis, int N){
  int i = blockIdx.x*256 + threadIdx.x;
  if(i < N){ float d = deg[i]; dis[i] = d > 0.f ? 1.0f/sqrtf(d) : 0.f; }
}

__global__ void k_scan_a(const float* __restrict__ deg, int* __restrict__ bsums, int N){
  __shared__ int ls[SBS/64];
  int base = blockIdx.x*SCHUNK + threadIdx.x*SIT;
  int s = 0;
  #pragma unroll
  for(int j=0;j<SIT;j++){ int i=base+j; if(i<N) s += (int)deg[i]; }
  #pragma unroll
  for(int o=32;o>0;o>>=1) s += __shfl_down(s,o);
  int lane = threadIdx.x & 63, w = threadIdx.x >> 6;
  if(lane==0) ls[w]=s;
  __syncthreads();
  if(threadIdx.x==0){ int t=0; for(int k2=0;k2<SBS/64;k2++) t+=ls[k2]; bsums[blockIdx.x]=t; }
}

__global__ void k_scan_b(const int* __restrict__ bsums, int* __restrict__ boffs,
                         int* __restrict__ rowptr, int NB, int N){
  int lane = threadIdx.x;
  int v = (lane < NB) ? bsums[lane] : 0;
  int incl = v;
  #pragma unroll
  for(int o=1;o<64;o<<=1){ int t = __shfl_up(incl,o); if(lane>=o) incl += t; }
  if(lane < NB) boffs[lane] = incl - v;
  if(lane == 63) rowptr[N] = incl;
}

__global__ void k_scan_c(const float* __restrict__ deg, const int* __restrict__ boffs,
                         int* __restrict__ rowptr, int* __restrict__ cur, int N){
  __shared__ int ts[SBS];
  int tid = threadIdx.x;
  int base = blockIdx.x*SCHUNK + tid*SIT;
  int v[SIT]; int s=0;
  #pragma unroll
  for(int j=0;j<SIT;j++){ int i=base+j; int d=(i<N)?(int)deg[i]:0; v[j]=s; s+=d; }
  ts[tid]=s; __syncthreads();
  for(int o=1;o<SBS;o<<=1){
    int t=(tid>=o)?ts[tid-o]:0; __syncthreads();
    ts[tid]+=t; __syncthreads();
  }
  int texcl = ts[tid]-s;
  int off = boffs[blockIdx.x]+texcl;
  #pragma unroll
  for(int j=0;j<SIT;j++){ int i=base+j; if(i<N){int r=off+v[j]; rowptr[i]=r; cur[i]=r;} }
}

__global__ void k_fill(const int* __restrict__ row, const int* __restrict__ col,
                       const float* __restrict__ dis, int* __restrict__ cur,
                       int* __restrict__ csrc, float* __restrict__ cw, int E){
  int e = blockIdx.x*256+threadIdx.x;
  if(e<E){
    int r=row[e], c=col[e];
    int p = atomicAdd(&cur[c],1);
    csrc[p]=r;
    cw[p]=dis[r]*dis[c];
  }
}

// ---------------- casts ----------------

__global__ void k_cast_x(const float* __restrict__ x, ushort* __restrict__ xb, int n4){
  int t = blockIdx.x*256 + threadIdx.x;
  if(t < n4){
    float4 v = ((const float4*)x)[t];
    uint2 o;
    o.x = (unsigned)f2bf(v.x) | ((unsigned)f2bf(v.y)<<16);
    o.y = (unsigned)f2bf(v.z) | ((unsigned)f2bf(v.w)<<16);
    ((uint2*)xb)[t] = o;
  }
}

// w1 [4][128][128] (s,kin,n) -> w1t [128][512] (n, s*128+kin)
__global__ void k_castw1(const float* __restrict__ w1, ushort* __restrict__ w1t){
  int i = blockIdx.x*256 + threadIdx.x;   // 65536
  int n = i & 127, kin = (i>>7)&127, s = i>>14;
  w1t[n*512 + s*128 + kin] = f2bf(w1[i]);
}

// w2 [4][128][40] -> w2t [256][128]: row np=s*64+nn, col k; pad nn>=40 with 0
__global__ void k_castw2(const float* __restrict__ w2, ushort* __restrict__ w2t){
  int i = blockIdx.x*256 + threadIdx.x;   // 32768
  int k = i & 127, np = i>>7;
  int s = np>>6, nn = np&63;
  float v = (nn<40) ? w2[(s*128 + k)*40 + nn] : 0.f;
  w2t[i] = f2bf(v);
}

// ---------------- SpMM width-128 bf16: dst[n] = sum w*src[r] ----------------

__global__ void __launch_bounds__(256) k_spmm1(
    const ushort* __restrict__ src, ushort* __restrict__ dst,
    const int* __restrict__ rowptr, const int* __restrict__ csrc,
    const float* __restrict__ cw, int N){
  int wid = threadIdx.x>>6, lane = threadIdx.x&63;
  int n = blockIdx.x*4 + wid;
  if(n>=N) return;
  int s = rowptr[n], e = rowptr[n+1];
  float ax=0.f, ay=0.f;
  for(int b=s; b<e; b+=64){
    int m = e-b; if(m>64) m=64;
    int idx=0; float wt=0.f;
    if(lane<m){ idx=csrc[b+lane]; wt=cw[b+lane]; }
    for(int j=0;j<m;j++){
      int r = __shfl(idx,j);
      float wg = __shfl(wt,j);
      unsigned v = *(const unsigned*)(src + (size_t)r*128 + lane*2);
      ax += wg*bflo(v); ay += wg*bfhi(v);
    }
  }
  unsigned o = (unsigned)f2bf(ax) | ((unsigned)f2bf(ay)<<16);
  *(unsigned*)(dst + (size_t)n*128 + lane*2) = o;
}

// ------- SpMM width-64(pad of 40) bf16 + add z: tnew[n] = A*tprev[n] + z[n] -------
// tprev row stride ss (ushorts); z row stride zs; tnew row stride 64.

__global__ void __launch_bounds__(256) k_spmm2(
    const ushort* __restrict__ tprev, int ss,
    const ushort* __restrict__ z, int zs,
    ushort* __restrict__ tnew,
    const int* __restrict__ rowptr, const int* __restrict__ csrc,
    const float* __restrict__ cw, int N){
  int wid = threadIdx.x>>6, lane = threadIdx.x&63;
  int n = blockIdx.x*4 + wid;
  if(n>=N) return;
  int p = lane>>5, c = lane&31;
  int s = rowptr[n], e = rowptr[n+1];
  float ax=0.f, ay=0.f;
  for(int b=s; b<e; b+=64){
    int m = e-b; if(m>64) m=64;
    int idx=0; float wt=0.f;
    if(lane<m){ idx=csrc[b+lane]; wt=cw[b+lane]; }
    for(int j=0;j<m;j+=2){
      int jj = j + p;
      int r = __shfl(idx, jj);
      float wg = (jj<m) ? __shfl(wt, jj) : 0.f;
      unsigned v = *(const unsigned*)(tprev + (size_t)r*ss + c*2);
      ax += wg*bflo(v); ay += wg*bfhi(v);
    }
  }
  ax += __shfl_xor(ax, 32);
  ay += __shfl_xor(ay, 32);
  unsigned vz = *(const unsigned*)(z + (size_t)n*zs + c*2);
  ax += bflo(vz); ay += bfhi(vz);
  if(p==0){
    unsigned o = (unsigned)f2bf(ax) | ((unsigned)f2bf(ay)<<16);
    *(unsigned*)(tnew + (size_t)n*64 + c*2) = o;
  }
}

// Final pass: out = log_softmax(A*tprev + z0) over cols 0..39, f32 out [N][40]

__global__ void __launch_bounds__(256) k_spmm2_lsm(
    const ushort* __restrict__ tprev, int ss,
    const ushort* __restrict__ z, int zs,
    float* __restrict__ out,
    const int* __restrict__ rowptr, const int* __restrict__ csrc,
    const float* __restrict__ cw, int N){
  int wid = threadIdx.x>>6, lane = threadIdx.x&63;
  int n = blockIdx.x*4 + wid;
  if(n>=N) return;
  int p = lane>>5, c = lane&31;
  int s = rowptr[n], e = rowptr[n+1];
  float ax=0.f, ay=0.f;
  for(int b=s; b<e; b+=64){
    int m = e-b; if(m>64) m=64;
    int idx=0; float wt=0.f;
    if(lane<m){ idx=csrc[b+lane]; wt=cw[b+lane]; }
    for(int j=0;j<m;j+=2){
      int jj = j + p;
      int r = __shfl(idx, jj);
      float wg = (jj<m) ? __shfl(wt, jj) : 0.f;
      unsigned v = *(const unsigned*)(tprev + (size_t)r*ss + c*2);
      ax += wg*bflo(v); ay += wg*bfhi(v);
    }
  }
  ax += __shfl_xor(ax, 32);
  ay += __shfl_xor(ay, 32);
  unsigned vz = *(const unsigned*)(z + (size_t)n*zs + c*2);
  ax += bflo(vz); ay += bfhi(vz);
  bool valid = (c < 20);                    // cols 2c,2c+1 < 40
  float vx = valid ? ax : -1e30f;
  float vy = valid ? ay : -1e30f;
  float mx = fmaxf(vx, vy);
  #pragma unroll
  for(int o=1;o<32;o<<=1) mx = fmaxf(mx, __shfl_xor(mx, o));
  float sum = valid ? (expf(vx-mx) + expf(vy-mx)) : 0.f;
  #pragma unroll
  for(int o=1;o<32;o<<=1) sum += __shfl_xor(sum, o);
  float l = logf(sum);
  if(p==0 && valid){
    float2 o2; o2.x = ax-mx-l; o2.y = ay-mx-l;
    *(float2*)(out + (size_t)n*40 + c*2) = o2;
  }
}

// ---------------- MFMA GEMM layer 1: out1 = relu([xb|h1|h2|h3] @ W1t^T + b1) ----------------
// A: N x 512 bf16 (4 concatenated sources), B: W1t [128 n][512 k], C: N x 128 bf16

#define LDA 72   // padded LDS stride (bf16 elems); 144B, octet-conflict-free

__global__ void __launch_bounds__(256) k_gemm1(
    const ushort* __restrict__ xb, const ushort* __restrict__ h1,
    const ushort* __restrict__ h2, const ushort* __restrict__ h3,
    const ushort* __restrict__ w1t, const float* __restrict__ bias,
    ushort* __restrict__ outb, int N){
  __shared__ ushort Al[128*LDA];
  __shared__ ushort Bl[128*LDA];
  int tid = threadIdx.x;
  int wid = tid>>6, lane = tid&63;
  int wr = wid>>1, wc = wid&1;
  int lm = lane&15, kg = lane>>4;
  int nbase = blockIdx.x*128;
  f32x4 acc[4][4];
  #pragma unroll
  for(int i=0;i<4;i++)
    #pragma unroll
    for(int j=0;j<4;j++) acc[i][j] = (f32x4){0.f,0.f,0.f,0.f};

  for(int kc=0; kc<8; kc++){
    const ushort* asrc = (kc<2) ? xb : (kc<4) ? h1 : (kc<6) ? h2 : h3;
    int koff = (kc&1)*64;
    __syncthreads();
    #pragma unroll
    for(int i=0;i<4;i++){
      int slot = tid + i*256;          // 1024 slots of 8 bf16
      int r = slot>>3, seg = (slot&7)*8;
      int n = nbase + r;
      uint4 v = make_uint4(0,0,0,0);
      if(n < N) v = *(const uint4*)(asrc + (size_t)n*128 + koff + seg);
      *(uint4*)(&Al[r*LDA + seg]) = v;
    }
    #pragma unroll
    for(int i=0;i<4;i++){
      int slot = tid + i*256;
      int r = slot>>3, seg = (slot&7)*8;
      uint4 v = *(const uint4*)(w1t + (size_t)r*512 + kc*64 + seg);
      *(uint4*)(&Bl[r*LDA + seg]) = v;
    }
    __syncthreads();
    #pragma unroll
    for(int ks=0; ks<2; ks++){
      bf16x8 a[4], b[4];
      #pragma unroll
      for(int f=0; f<4; f++){
        a[f] = *(const bf16x8*)&Al[(wr*64 + f*16 + lm)*LDA + ks*32 + kg*8];
        b[f] = *(const bf16x8*)&Bl[(wc*64 + f*16 + lm)*LDA + ks*32 + kg*8];
      }
      #pragma unroll
      for(int fm=0; fm<4; fm++)
        #pragma unroll
        for(int fn=0; fn<4; fn++)
          acc[fm][fn] = __builtin_amdgcn_mfma_f32_16x16x32_bf16(a[fm], b[fn], acc[fm][fn], 0,0,0);
    }
  }
  int crow0 = (lane>>4)*4;
  #pragma unroll
  for(int fm=0; fm<4; fm++){
    #pragma unroll
    for(int fn=0; fn<4; fn++){
      int col = wc*64 + fn*16 + lm;
      float bv = bias[col];
      #pragma unroll
      for(int j=0;j<4;j++){
        int row = nbase + wr*64 + fm*16 + crow0 + j;
        if(row < N){
          float v = fmaxf(acc[fm][fn][j] + bv, 0.f);
          outb[(size_t)row*128 + col] = f2bf(v);
        }
      }
    }
  }
}

// ------- MFMA GEMM layer 2: zstack[N][256] = out1b @ W2t^T (+b2 on cols<40) -------

__global__ void __launch_bounds__(256) k_gemm2(
    const ushort* __restrict__ ab, const ushort* __restrict__ w2t,
    const float* __restrict__ bias, ushort* __restrict__ z, int N){
  __shared__ ushort Al[128*LDA];
  __shared__ ushort Bl[128*LDA];
  int tid = threadIdx.x;
  int wid = tid>>6, lane = tid&63;
  int wr = wid>>1, wc = wid&1;
  int lm = lane&15, kg = lane>>4;
  int nbase = blockIdx.x*128;
  int cb = blockIdx.y;                 // column block: cols cb*128..+128
  f32x4 acc[4][4];
  #pragma unroll
  for(int i=0;i<4;i++)
    #pragma unroll
    for(int j=0;j<4;j++) acc[i][j] = (f32x4){0.f,0.f,0.f,0.f};

  for(int kc=0; kc<2; kc++){
    int koff = kc*64;
    __syncthreads();
    #pragma unroll
    for(int i=0;i<4;i++){
      int slot = tid + i*256;
      int r = slot>>3, seg = (slot&7)*8;
      int n = nbase + r;
      uint4 v = make_uint4(0,0,0,0);
      if(n < N) v = *(const uint4*)(ab + (size_t)n*128 + koff + seg);
      *(uint4*)(&Al[r*LDA + seg]) = v;
    }
    #pragma unroll
    for(int i=0;i<4;i++){
      int slot = tid + i*256;
      int r = slot>>3, seg = (slot&7)*8;
      uint4 v = *(const uint4*)(w2t + (size_t)(cb*128 + r)*128 + koff + seg);
      *(uint4*)(&Bl[r*LDA + seg]) = v;
    }
    __syncthreads();
    #pragma unroll
    for(int ks=0; ks<2; ks++){
      bf16x8 a[4], b[4];
      #pragma unroll
      for(int f=0; f<4; f++){
        a[f] = *(const bf16x8*)&Al[(wr*64 + f*16 + lm)*LDA + ks*32 + kg*8];
        b[f] = *(const bf16x8*)&Bl[(wc*64 + f*16 + lm)*LDA + ks*32 + kg*8];
      }
      #pragma unroll
      for(int fm=0; fm<4; fm++)
        #pragma unroll
        for(int fn=0; fn<4; fn++)
          acc[fm][fn] = __builtin_amdgcn_mfma_f32_16x16x32_bf16(a[fm], b[fn], acc[fm][fn], 0,0,0);
    }
  }
  int crow0 = (lane>>4)*4;
  #pragma unroll
  for(int fm=0; fm<4; fm++){
    #pragma unroll
    for(int fn=0; fn<4; fn++){
      int cc = cb*128 + wc*64 + fn*16 + lm;
      float bv = (cc < 40) ? bias[cc] : 0.f;
      #pragma unroll
      for(int j=0;j<4;j++){
        int row = nbase + wr*64 + fm*16 + crow0 + j;
        if(row < N){
          float v = acc[fm][fn][j] + bv;
          z[(size_t)row*256 + cc] = f2bf(v);
        }
      }
    }
  }
}

// ---------------- host ----------------

extern "C" void kernel_launch(void* const* d_in, const int* in_sizes, int n_in,
                              void* d_out, int out_size, void* d_ws, size_t ws_size,
                              hipStream_t stream){
  const float* x  = (const float*)d_in[0];
  const int*   ei = (const int*)d_in[1];
  const float* w1 = (const float*)d_in[2];
  const float* b1 = (const float*)d_in[3];
  const float* w2 = (const float*)d_in[4];
  const float* b2 = (const float*)d_in[5];
  float* out = (float*)d_out;
  int N = in_sizes[0] / 128;
  int E = in_sizes[1] / 2;
  const int* rowv = ei;
  const int* colv = ei + E;

  char* wsp = (char*)d_ws;
  size_t off = 0;
  auto alloc = [&](size_t bytes)->void*{
    void* p = wsp + off;
    off = (off + bytes + 255) & ~(size_t)255;
    return p;
  };
  float*  deg    = (float*) alloc((size_t)N*4);
  float*  dis    = (float*) alloc((size_t)N*4);
  int*    rowptr = (int*)   alloc((size_t)(N+1)*4);
  int*    cur    = (int*)   alloc((size_t)N*4);
  int*    bsums  = (int*)   alloc(512);
  int*    boffs  = (int*)   alloc(512);
  int*    csrc   = (int*)   alloc((size_t)E*4);
  float*  cw     = (float*) alloc((size_t)E*4);
  ushort* xb     = (ushort*)alloc((size_t)N*128*2);
  ushort* hb1    = (ushort*)alloc((size_t)N*128*2);
  ushort* hb2    = (ushort*)alloc((size_t)N*128*2);
  ushort* hb3    = (ushort*)alloc((size_t)N*128*2);
  ushort* out1b  = (ushort*)alloc((size_t)N*128*2);
  ushort* w1t    = (ushort*)alloc(128*512*2);
  ushort* w2t    = (ushort*)alloc(256*128*2);
  ushort* zst    = (ushort*)alloc((size_t)N*256*2);
  // t buffers reuse hb1/hb2 space (dead after k_gemm1)
  ushort* ta     = hb1;
  ushort* tb     = hb2;
  (void)ws_size;

  int eb = (E+255)/256;
  int nb = (N+SCHUNK-1)/SCHUNK;

  hipMemsetAsync(deg, 0, (size_t)N*4, stream);
  k_count <<<eb, 256, 0, stream>>>(colv, deg, E);
  k_dis   <<<(N+255)/256, 256, 0, stream>>>(deg, dis, N);
  k_scan_a<<<nb, SBS, 0, stream>>>(deg, bsums, N);
  k_scan_b<<<1, 64, 0, stream>>>(bsums, boffs, rowptr, nb, N);
  k_scan_c<<<nb, SBS, 0, stream>>>(deg, boffs, rowptr, cur, N);
  k_fill  <<<eb, 256, 0, stream>>>(rowv, colv, dis, cur, csrc, cw, E);

  k_cast_x <<<(N*32+255)/256, 256, 0, stream>>>(x, xb, N*32);
  k_castw1 <<<256, 256, 0, stream>>>(w1, w1t);
  k_castw2 <<<128, 256, 0, stream>>>(w2, w2t);

  int sg = (N+3)/4;
  int gb = (N+127)/128;
  // layer 1: propagate width-128 bf16
  k_spmm1<<<sg, 256, 0, stream>>>(xb,  hb1, rowptr, csrc, cw, N);
  k_spmm1<<<sg, 256, 0, stream>>>(hb1, hb2, rowptr, csrc, cw, N);
  k_spmm1<<<sg, 256, 0, stream>>>(hb2, hb3, rowptr, csrc, cw, N);
  k_gemm1<<<gb, 256, 0, stream>>>(xb, hb1, hb2, hb3, w1t, b1, out1b, N);
  // layer 2: z_k = H @ W2_k (one GEMM, N x 256), then Horner propagation at width 64
  k_gemm2<<<dim3(gb,2), 256, 0, stream>>>(out1b, w2t, b2, zst, N);
  // out = z0 + A(z1 + A(z2 + A z3))
  k_spmm2    <<<sg, 256, 0, stream>>>(zst+192, 256, zst+128, 256, ta, rowptr, csrc, cw, N);
  k_spmm2    <<<sg, 256, 0, stream>>>(ta,       64, zst+64, 256, tb, rowptr, csrc, cw, N);
  k_spmm2_lsm<<<sg, 256, 0, stream>>>(tb,       64, zst,    256, out, rowptr, csrc, cw, N);
}

// Round 4
// 585.925 us; speedup vs baseline: 2.2298x; 1.3757x over previous
//
#include <hip/hip_runtime.h>
#include <math.h>

#define SBS 256
#define SIT 8
#define SCHUNK (SBS*SIT)

typedef __bf16 bf16x8 __attribute__((ext_vector_type(8)));
typedef float  f32x4  __attribute__((ext_vector_type(4)));

__device__ __forceinline__ unsigned short f2bf(float f){
  unsigned u = __float_as_uint(f);
  unsigned r = (u + 0x7fffu + ((u>>16)&1u)) >> 16;
  return (unsigned short)r;
}
__device__ __forceinline__ float bflo(unsigned v){ return __uint_as_float(v<<16); }
__device__ __forceinline__ float bfhi(unsigned v){ return __uint_as_float(v & 0xffff0000u); }

// ---------------- gcn_norm preprocessing ----------------

__global__ void k_count(const int* __restrict__ col, int* __restrict__ deg, int E){
  int e = blockIdx.x*256 + threadIdx.x;
  if(e < E) atomicAdd(&deg[col[e]], 1);
}

__global__ void k_dis(const int* __restrict__ deg, float* __restrict__ dis, int N){
  int i = blockIdx.x*256 + threadIdx.x;
  if(i < N){ int d = deg[i]; dis[i] = d > 0 ? rsqrtf((float)d) : 0.f; }
}

__global__ void k_scan_a(const int* __restrict__ deg, int* __restrict__ bsums, int N){
  __shared__ int ls[SBS/64];
  int base = blockIdx.x*SCHUNK + threadIdx.x*SIT;
  int s = 0;
  #pragma unroll
  for(int j=0;j<SIT;j++){ int i=base+j; if(i<N) s += deg[i]; }
  #pragma unroll
  for(int o=32;o>0;o>>=1) s += __shfl_down(s,o);
  int lane = threadIdx.x & 63, w = threadIdx.x >> 6;
  if(lane==0) ls[w]=s;
  __syncthreads();
  if(threadIdx.x==0){ int t=0; for(int k2=0;k2<SBS/64;k2++) t+=ls[k2]; bsums[blockIdx.x]=t; }
}

__global__ void k_scan_b(const int* __restrict__ bsums, int* __restrict__ boffs,
                         int* __restrict__ rowptr, int NB, int N){
  int lane = threadIdx.x;
  int v = (lane < NB) ? bsums[lane] : 0;
  int incl = v;
  #pragma unroll
  for(int o=1;o<64;o<<=1){ int t = __shfl_up(incl,o); if(lane>=o) incl += t; }
  if(lane < NB) boffs[lane] = incl - v;
  if(lane == 63) rowptr[N] = incl;
}

__global__ void k_scan_c(const int* __restrict__ deg, const int* __restrict__ boffs,
                         int* __restrict__ rowptr, int* __restrict__ cur, int N){
  __shared__ int ts[SBS];
  int tid = threadIdx.x;
  int base = blockIdx.x*SCHUNK + tid*SIT;
  int v[SIT]; int s=0;
  #pragma unroll
  for(int j=0;j<SIT;j++){ int i=base+j; int d=(i<N)?deg[i]:0; v[j]=s; s+=d; }
  ts[tid]=s; __syncthreads();
  for(int o=1;o<SBS;o<<=1){
    int t=(tid>=o)?ts[tid-o]:0; __syncthreads();
    ts[tid]+=t; __syncthreads();
  }
  int texcl = ts[tid]-s;
  int off = boffs[blockIdx.x]+texcl;
  #pragma unroll
  for(int j=0;j<SIT;j++){ int i=base+j; if(i<N){int r=off+v[j]; rowptr[i]=r; cur[i]=r;} }
}

__global__ void k_fill(const int* __restrict__ row, const int* __restrict__ col,
                       const float* __restrict__ dis, int* __restrict__ cur,
                       uint2* __restrict__ ed, int E){
  int e = blockIdx.x*256+threadIdx.x;
  if(e<E){
    int r=row[e], c=col[e];
    int p = atomicAdd(&cur[c],1);
    uint2 v; v.x = (unsigned)r; v.y = __float_as_uint(dis[r]*dis[c]);
    ed[p] = v;
  }
}

// ---------------- casts ----------------

__global__ void k_cast_x(const float* __restrict__ x, ushort* __restrict__ xb, int n4){
  int t = blockIdx.x*256 + threadIdx.x;
  if(t < n4){
    float4 v = ((const float4*)x)[t];
    uint2 o;
    o.x = (unsigned)f2bf(v.x) | ((unsigned)f2bf(v.y)<<16);
    o.y = (unsigned)f2bf(v.z) | ((unsigned)f2bf(v.w)<<16);
    ((uint2*)xb)[t] = o;
  }
}

// w1 [4][128][128] (s,kin,n) -> w1t [128][512] (n, s*128+kin)
__global__ void k_castw1(const float* __restrict__ w1, ushort* __restrict__ w1t){
  int i = blockIdx.x*256 + threadIdx.x;   // 65536
  int n = i & 127, kin = (i>>7)&127, s = i>>14;
  w1t[n*512 + s*128 + kin] = f2bf(w1[i]);
}

// w2 [4][128][40] -> w2t [256][128]: row np=s*64+nn, col k; pad nn>=40 with 0
__global__ void k_castw2(const float* __restrict__ w2, ushort* __restrict__ w2t){
  int i = blockIdx.x*256 + threadIdx.x;   // 32768
  int k = i & 127, np = i>>7;
  int s = np>>6, nn = np&63;
  float v = (nn<40) ? w2[(s*128 + k)*40 + nn] : 0.f;
  w2t[i] = f2bf(v);
}

// ------- SpMM width-128 bf16: dst[n] = sum w*src[r]; 4 edges in flight -------

__global__ void __launch_bounds__(256) k_spmm1(
    const ushort* __restrict__ src, ushort* __restrict__ dst,
    const int* __restrict__ rowptr, const uint2* __restrict__ ed, int N){
  int wid = threadIdx.x>>6, lane = threadIdx.x&63;
  int n = blockIdx.x*4 + wid;
  if(n>=N) return;
  int p = lane>>4, c = lane&15;      // group p handles edges j%4==p; cols 8c..8c+7
  int s = rowptr[n], e = rowptr[n+1];
  float a[8];
  #pragma unroll
  for(int i=0;i<8;i++) a[i]=0.f;
  for(int b=s; b<e; b+=64){
    int m = e-b; if(m>64) m=64;
    uint2 eD = make_uint2(0u,0u);
    if(lane<m) eD = ed[b+lane];
    int tmax = (m+3)>>2;
    for(int t=0;t<tmax;t++){
      int j = 4*t + p;
      int r = __shfl((int)eD.x, j);
      float wg = __uint_as_float(__shfl((int)eD.y, j));
      uint4 v = *(const uint4*)(src + (size_t)r*128 + c*8);
      a[0]+=wg*bflo(v.x); a[1]+=wg*bfhi(v.x);
      a[2]+=wg*bflo(v.y); a[3]+=wg*bfhi(v.y);
      a[4]+=wg*bflo(v.z); a[5]+=wg*bfhi(v.z);
      a[6]+=wg*bflo(v.w); a[7]+=wg*bfhi(v.w);
    }
  }
  #pragma unroll
  for(int i=0;i<8;i++){ a[i]+=__shfl_xor(a[i],32); a[i]+=__shfl_xor(a[i],16); }
  if(p==0){
    uint4 o;
    o.x = (unsigned)f2bf(a[0]) | ((unsigned)f2bf(a[1])<<16);
    o.y = (unsigned)f2bf(a[2]) | ((unsigned)f2bf(a[3])<<16);
    o.z = (unsigned)f2bf(a[4]) | ((unsigned)f2bf(a[5])<<16);
    o.w = (unsigned)f2bf(a[6]) | ((unsigned)f2bf(a[7])<<16);
    *(uint4*)(dst + (size_t)n*128 + c*8) = o;
  }
}

// ------- SpMM width-64 + add z: tnew[n] = A*tprev[n] + z[n]; 8 edges in flight -------

__global__ void __launch_bounds__(256) k_spmm2(
    const ushort* __restrict__ tprev, int ss,
    const ushort* __restrict__ z, int zs,
    ushort* __restrict__ tnew,
    const int* __restrict__ rowptr, const uint2* __restrict__ ed, int N){
  int wid = threadIdx.x>>6, lane = threadIdx.x&63;
  int n = blockIdx.x*4 + wid;
  if(n>=N) return;
  int p = lane>>3, c = lane&7;       // group p handles edges j%8==p; cols 8c..8c+7
  int s = rowptr[n], e = rowptr[n+1];
  float a[8];
  #pragma unroll
  for(int i=0;i<8;i++) a[i]=0.f;
  for(int b=s; b<e; b+=64){
    int m = e-b; if(m>64) m=64;
    uint2 eD = make_uint2(0u,0u);
    if(lane<m) eD = ed[b+lane];
    int tmax = (m+7)>>3;
    for(int t=0;t<tmax;t++){
      int j = 8*t + p;
      int r = __shfl((int)eD.x, j);
      float wg = __uint_as_float(__shfl((int)eD.y, j));
      uint4 v = *(const uint4*)(tprev + (size_t)r*ss + c*8);
      a[0]+=wg*bflo(v.x); a[1]+=wg*bfhi(v.x);
      a[2]+=wg*bflo(v.y); a[3]+=wg*bfhi(v.y);
      a[4]+=wg*bflo(v.z); a[5]+=wg*bfhi(v.z);
      a[6]+=wg*bflo(v.w); a[7]+=wg*bfhi(v.w);
    }
  }
  #pragma unroll
  for(int i=0;i<8;i++){ a[i]+=__shfl_xor(a[i],32); a[i]+=__shfl_xor(a[i],16); a[i]+=__shfl_xor(a[i],8); }
  if(lane<8){
    uint4 vz = *(const uint4*)(z + (size_t)n*zs + c*8);
    a[0]+=bflo(vz.x); a[1]+=bfhi(vz.x);
    a[2]+=bflo(vz.y); a[3]+=bfhi(vz.y);
    a[4]+=bflo(vz.z); a[5]+=bfhi(vz.z);
    a[6]+=bflo(vz.w); a[7]+=bfhi(vz.w);
    uint4 o;
    o.x = (unsigned)f2bf(a[0]) | ((unsigned)f2bf(a[1])<<16);
    o.y = (unsigned)f2bf(a[2]) | ((unsigned)f2bf(a[3])<<16);
    o.z = (unsigned)f2bf(a[4]) | ((unsigned)f2bf(a[5])<<16);
    o.w = (unsigned)f2bf(a[6]) | ((unsigned)f2bf(a[7])<<16);
    *(uint4*)(tnew + (size_t)n*64 + c*8) = o;
  }
}

// Final: out = log_softmax(A*tprev + z0) over cols 0..39, f32 out [N][40]

__global__ void __launch_bounds__(256) k_spmm2_lsm(
    const ushort* __restrict__ tprev, int ss,
    const ushort* __restrict__ z, int zs,
    float* __restrict__ out,
    const int* __restrict__ rowptr, const uint2* __restrict__ ed, int N){
  int wid = threadIdx.x>>6, lane = threadIdx.x&63;
  int n = blockIdx.x*4 + wid;
  if(n>=N) return;
  int p = lane>>3, c = lane&7;
  int s = rowptr[n], e = rowptr[n+1];
  float a[8];
  #pragma unroll
  for(int i=0;i<8;i++) a[i]=0.f;
  for(int b=s; b<e; b+=64){
    int m = e-b; if(m>64) m=64;
    uint2 eD = make_uint2(0u,0u);
    if(lane<m) eD = ed[b+lane];
    int tmax = (m+7)>>3;
    for(int t=0;t<tmax;t++){
      int j = 8*t + p;
      int r = __shfl((int)eD.x, j);
      float wg = __uint_as_float(__shfl((int)eD.y, j));
      uint4 v = *(const uint4*)(tprev + (size_t)r*ss + c*8);
      a[0]+=wg*bflo(v.x); a[1]+=wg*bfhi(v.x);
      a[2]+=wg*bflo(v.y); a[3]+=wg*bfhi(v.y);
      a[4]+=wg*bflo(v.z); a[5]+=wg*bfhi(v.z);
      a[6]+=wg*bflo(v.w); a[7]+=wg*bfhi(v.w);
    }
  }
  #pragma unroll
  for(int i=0;i<8;i++){ a[i]+=__shfl_xor(a[i],32); a[i]+=__shfl_xor(a[i],16); a[i]+=__shfl_xor(a[i],8); }
  uint4 vz = *(const uint4*)(z + (size_t)n*zs + c*8);
  a[0]+=bflo(vz.x); a[1]+=bfhi(vz.x);
  a[2]+=bflo(vz.y); a[3]+=bfhi(vz.y);
  a[4]+=bflo(vz.z); a[5]+=bfhi(vz.z);
  a[6]+=bflo(vz.w); a[7]+=bfhi(vz.w);
  // softmax over 40 valid cols: lanes c<5 hold cols 8c..8c+7
  bool valid = (c < 5);
  float mx = -1e30f;
  #pragma unroll
  for(int i=0;i<8;i++) if(valid) mx = fmaxf(mx, a[i]);
  #pragma unroll
  for(int o=1;o<8;o<<=1) mx = fmaxf(mx, __shfl_xor(mx, o));
  float sum = 0.f;
  #pragma unroll
  for(int i=0;i<8;i++) if(valid) sum += expf(a[i]-mx);
  #pragma unroll
  for(int o=1;o<8;o<<=1) sum += __shfl_xor(sum, o);
  float l = mx + logf(sum);
  if(lane<8 && valid){
    float4 o0, o1;
    o0.x=a[0]-l; o0.y=a[1]-l; o0.z=a[2]-l; o0.w=a[3]-l;
    o1.x=a[4]-l; o1.y=a[5]-l; o1.z=a[6]-l; o1.w=a[7]-l;
    float* op = out + (size_t)n*40 + c*8;
    *(float4*)op = o0;
    *(float4*)(op+4) = o1;
  }
}

// ---------------- MFMA GEMM layer 1 ----------------

#define LDA 72

__global__ void __launch_bounds__(256) k_gemm1(
    const ushort* __restrict__ xb, const ushort* __restrict__ h1,
    const ushort* __restrict__ h2, const ushort* __restrict__ h3,
    const ushort* __restrict__ w1t, const float* __restrict__ bias,
    ushort* __restrict__ outb, int N){
  __shared__ ushort Al[128*LDA];
  __shared__ ushort Bl[128*LDA];
  int tid = threadIdx.x;
  int wid = tid>>6, lane = tid&63;
  int wr = wid>>1, wc = wid&1;
  int lm = lane&15, kg = lane>>4;
  int nbase = blockIdx.x*128;
  f32x4 acc[4][4];
  #pragma unroll
  for(int i=0;i<4;i++)
    #pragma unroll
    for(int j=0;j<4;j++) acc[i][j] = (f32x4){0.f,0.f,0.f,0.f};

  for(int kc=0; kc<8; kc++){
    const ushort* asrc = (kc<2) ? xb : (kc<4) ? h1 : (kc<6) ? h2 : h3;
    int koff = (kc&1)*64;
    __syncthreads();
    #pragma unroll
    for(int i=0;i<4;i++){
      int slot = tid + i*256;
      int r = slot>>3, seg = (slot&7)*8;
      int n = nbase + r;
      uint4 v = make_uint4(0,0,0,0);
      if(n < N) v = *(const uint4*)(asrc + (size_t)n*128 + koff + seg);
      *(uint4*)(&Al[r*LDA + seg]) = v;
    }
    #pragma unroll
    for(int i=0;i<4;i++){
      int slot = tid + i*256;
      int r = slot>>3, seg = (slot&7)*8;
      uint4 v = *(const uint4*)(w1t + (size_t)r*512 + kc*64 + seg);
      *(uint4*)(&Bl[r*LDA + seg]) = v;
    }
    __syncthreads();
    #pragma unroll
    for(int ks=0; ks<2; ks++){
      bf16x8 a[4], b[4];
      #pragma unroll
      for(int f=0; f<4; f++){
        a[f] = *(const bf16x8*)&Al[(wr*64 + f*16 + lm)*LDA + ks*32 + kg*8];
        b[f] = *(const bf16x8*)&Bl[(wc*64 + f*16 + lm)*LDA + ks*32 + kg*8];
      }
      #pragma unroll
      for(int fm=0; fm<4; fm++)
        #pragma unroll
        for(int fn=0; fn<4; fn++)
          acc[fm][fn] = __builtin_amdgcn_mfma_f32_16x16x32_bf16(a[fm], b[fn], acc[fm][fn], 0,0,0);
    }
  }
  int crow0 = (lane>>4)*4;
  #pragma unroll
  for(int fm=0; fm<4; fm++){
    #pragma unroll
    for(int fn=0; fn<4; fn++){
      int col = wc*64 + fn*16 + lm;
      float bv = bias[col];
      #pragma unroll
      for(int j=0;j<4;j++){
        int row = nbase + wr*64 + fm*16 + crow0 + j;
        if(row < N){
          float v = fmaxf(acc[fm][fn][j] + bv, 0.f);
          outb[(size_t)row*128 + col] = f2bf(v);
        }
      }
    }
  }
}

// ------- MFMA GEMM layer 2: zstack[N][256] = out1b @ W2t^T (+b2 on cols<40) -------

__global__ void __launch_bounds__(256) k_gemm2(
    const ushort* __restrict__ ab, const ushort* __restrict__ w2t,
    const float* __restrict__ bias, ushort* __restrict__ z, int N){
  __shared__ ushort Al[128*LDA];
  __shared__ ushort Bl[128*LDA];
  int tid = threadIdx.x;
  int wid = tid>>6, lane = tid&63;
  int wr = wid>>1, wc = wid&1;
  int lm = lane&15, kg = lane>>4;
  int nbase = blockIdx.x*128;
  int cb = blockIdx.y;
  f32x4 acc[4][4];
  #pragma unroll
  for(int i=0;i<4;i++)
    #pragma unroll
    for(int j=0;j<4;j++) acc[i][j] = (f32x4){0.f,0.f,0.f,0.f};

  for(int kc=0; kc<2; kc++){
    int koff = kc*64;
    __syncthreads();
    #pragma unroll
    for(int i=0;i<4;i++){
      int slot = tid + i*256;
      int r = slot>>3, seg = (slot&7)*8;
      int n = nbase + r;
      uint4 v = make_uint4(0,0,0,0);
      if(n < N) v = *(const uint4*)(ab + (size_t)n*128 + koff + seg);
      *(uint4*)(&Al[r*LDA + seg]) = v;
    }
    #pragma unroll
    for(int i=0;i<4;i++){
      int slot = tid + i*256;
      int r = slot>>3, seg = (slot&7)*8;
      uint4 v = *(const uint4*)(w2t + (size_t)(cb*128 + r)*128 + koff + seg);
      *(uint4*)(&Bl[r*LDA + seg]) = v;
    }
    __syncthreads();
    #pragma unroll
    for(int ks=0; ks<2; ks++){
      bf16x8 a[4], b[4];
      #pragma unroll
      for(int f=0; f<4; f++){
        a[f] = *(const bf16x8*)&Al[(wr*64 + f*16 + lm)*LDA + ks*32 + kg*8];
        b[f] = *(const bf16x8*)&Bl[(wc*64 + f*16 + lm)*LDA + ks*32 + kg*8];
      }
      #pragma unroll
      for(int fm=0; fm<4; fm++)
        #pragma unroll
        for(int fn=0; fn<4; fn++)
          acc[fm][fn] = __builtin_amdgcn_mfma_f32_16x16x32_bf16(a[fm], b[fn], acc[fm][fn], 0,0,0);
    }
  }
  int crow0 = (lane>>4)*4;
  #pragma unroll
  for(int fm=0; fm<4; fm++){
    #pragma unroll
    for(int fn=0; fn<4; fn++){
      int cc = cb*128 + wc*64 + fn*16 + lm;
      float bv = (cc < 40) ? bias[cc] : 0.f;
      #pragma unroll
      for(int j=0;j<4;j++){
        int row = nbase + wr*64 + fm*16 + crow0 + j;
        if(row < N){
          float v = acc[fm][fn][j] + bv;
          z[(size_t)row*256 + cc] = f2bf(v);
        }
      }
    }
  }
}

// ---------------- host ----------------

extern "C" void kernel_launch(void* const* d_in, const int* in_sizes, int n_in,
                              void* d_out, int out_size, void* d_ws, size_t ws_size,
                              hipStream_t stream){
  const float* x  = (const float*)d_in[0];
  const int*   ei = (const int*)d_in[1];
  const float* w1 = (const float*)d_in[2];
  const float* b1 = (const float*)d_in[3];
  const float* w2 = (const float*)d_in[4];
  const float* b2 = (const float*)d_in[5];
  float* out = (float*)d_out;
  int N = in_sizes[0] / 128;
  int E = in_sizes[1] / 2;
  const int* rowv = ei;
  const int* colv = ei + E;

  char* wsp = (char*)d_ws;
  size_t off = 0;
  auto alloc = [&](size_t bytes)->void*{
    void* p = wsp + off;
    off = (off + bytes + 255) & ~(size_t)255;
    return p;
  };
  int*    deg    = (int*)   alloc((size_t)N*4);
  float*  dis    = (float*) alloc((size_t)N*4);
  int*    rowptr = (int*)   alloc((size_t)(N+1)*4);
  int*    cur    = (int*)   alloc((size_t)N*4);
  int*    bsums  = (int*)   alloc(512);
  int*    boffs  = (int*)   alloc(512);
  uint2*  ed     = (uint2*) alloc((size_t)E*8);
  ushort* xb     = (ushort*)alloc((size_t)N*128*2);
  ushort* hb1    = (ushort*)alloc((size_t)N*128*2);
  ushort* hb2    = (ushort*)alloc((size_t)N*128*2);
  ushort* hb3    = (ushort*)alloc((size_t)N*128*2);
  ushort* out1b  = (ushort*)alloc((size_t)N*128*2);
  ushort* w1t    = (ushort*)alloc(128*512*2);
  ushort* w2t    = (ushort*)alloc(256*128*2);
  ushort* zst    = (ushort*)alloc((size_t)N*256*2);
  ushort* ta     = hb1;
  ushort* tb     = hb2;
  (void)ws_size;

  int eb = (E+255)/256;
  int nb = (N+SCHUNK-1)/SCHUNK;

  hipMemsetAsync(deg, 0, (size_t)N*4, stream);
  k_count <<<eb, 256, 0, stream>>>(colv, deg, E);
  k_dis   <<<(N+255)/256, 256, 0, stream>>>(deg, dis, N);
  k_scan_a<<<nb, SBS, 0, stream>>>(deg, bsums, N);
  k_scan_b<<<1, 64, 0, stream>>>(bsums, boffs, rowptr, nb, N);
  k_scan_c<<<nb, SBS, 0, stream>>>(deg, boffs, rowptr, cur, N);
  k_fill  <<<eb, 256, 0, stream>>>(rowv, colv, dis, cur, ed, E);

  k_cast_x <<<(N*32+255)/256, 256, 0, stream>>>(x, xb, N*32);
  k_castw1 <<<256, 256, 0, stream>>>(w1, w1t);
  k_castw2 <<<128, 256, 0, stream>>>(w2, w2t);

  int sg = (N+3)/4;
  int gb = (N+127)/128;
  // layer 1: propagate width-128 bf16
  k_spmm1<<<sg, 256, 0, stream>>>(xb,  hb1, rowptr, ed, N);
  k_spmm1<<<sg, 256, 0, stream>>>(hb1, hb2, rowptr, ed, N);
  k_spmm1<<<sg, 256, 0, stream>>>(hb2, hb3, rowptr, ed, N);
  k_gemm1<<<gb, 256, 0, stream>>>(xb, hb1, hb2, hb3, w1t, b1, out1b, N);
  // layer 2: z_k = H @ W2_k, then Horner propagation at width 64
  k_gemm2<<<dim3(gb,2), 256, 0, stream>>>(out1b, w2t, b2, zst, N);
  k_spmm2    <<<sg, 256, 0, stream>>>(zst+192, 256, zst+128, 256, ta, rowptr, ed, N);
  k_spmm2    <<<sg, 256, 0, stream>>>(ta,       64, zst+64, 256, tb, rowptr, ed, N);
  k_spmm2_lsm<<<sg, 256, 0, stream>>>(tb,       64, zst,    256, out, rowptr, ed, N);
}